// Round 3
// baseline (160.663 us; speedup 1.0000x reference)
//
#include <hip/hip_runtime.h>

typedef float f32x4  __attribute__((ext_vector_type(4)));
typedef float f32x16 __attribute__((ext_vector_type(16)));
typedef short s16x8  __attribute__((ext_vector_type(8)));
typedef unsigned short u16;

#define LL 2048
#define DD 64
#define NITER 32
#define SC_OFF 4194304ull
#define TEN ((size_t)4194304)   // elements per tensor (B*H*L*D)

struct SMem {
    u16   Khi[64][72];           // key tile, bf16, padded stride 144B (bank-balanced)
    u16   VT [64][72];           // V^T tile (d rows, c cols), bf16
    float bias[64];              // -1e9 * mask per key of this tile
    union {
        u16 Q[128][72];          // f32-fallback prologue staging
        unsigned char P[4][4096];// per-iw P tile [i 0..31][c 0..63] bf16, XOR-swizzled rows
    } u;
};

__device__ __forceinline__ u16 bf16_rne(float x) {
    unsigned u = __builtin_bit_cast(unsigned, x);
    return (u16)((u + 0x7FFFu + ((u >> 16) & 1u)) >> 16);
}
__device__ __forceinline__ float bf16f(u16 h) {
    unsigned u = (unsigned)h << 16;
    return __builtin_bit_cast(float, u);
}

// ---- prepass: f32 -> bf16 (Q split hi+lo; K,V single-rounded), row-major ----
__global__ __launch_bounds__(256)
void psam_prepass(const float* __restrict__ q, const float* __restrict__ k,
                  const float* __restrict__ v, u16* __restrict__ qhi,
                  u16* __restrict__ qlo, u16* __restrict__ k16,
                  u16* __restrict__ v16)
{
    const size_t i = ((size_t)blockIdx.x * 256 + threadIdx.x) * 8;
    {
        f32x4 a = *(const f32x4*)(q + i), b = *(const f32x4*)(q + i + 4);
        s16x8 hi, lo;
#pragma unroll
        for (int e = 0; e < 4; ++e) {
            u16 hh = bf16_rne(a[e]); hi[e] = (short)hh; lo[e] = (short)bf16_rne(a[e] - bf16f(hh));
            hh = bf16_rne(b[e]); hi[4 + e] = (short)hh; lo[4 + e] = (short)bf16_rne(b[e] - bf16f(hh));
        }
        *(s16x8*)(qhi + i) = hi;
        *(s16x8*)(qlo + i) = lo;
    }
    {
        f32x4 a = *(const f32x4*)(k + i), b = *(const f32x4*)(k + i + 4);
        s16x8 kk;
#pragma unroll
        for (int e = 0; e < 4; ++e) { kk[e] = (short)bf16_rne(a[e]); kk[4 + e] = (short)bf16_rne(b[e]); }
        *(s16x8*)(k16 + i) = kk;
    }
    {
        f32x4 a = *(const f32x4*)(v + i), b = *(const f32x4*)(v + i + 4);
        s16x8 vv;
#pragma unroll
        for (int e = 0; e < 4; ++e) { vv[e] = (short)bf16_rne(a[e]); vv[4 + e] = (short)bf16_rne(b[e]); }
        *(s16x8*)(v16 + i) = vv;
    }
}

template<int BF>
__global__ __launch_bounds__(512, 4)
void psam_kernel(const void* __restrict__ Qa, const void* __restrict__ Qb,
                 const void* __restrict__ Ka, const void* __restrict__ Va,
                 const int* __restrict__ Mg0, float* __restrict__ out)
{
    __shared__ SMem sm;
    const int tid = threadIdx.x;
    const int w = tid >> 6, l = tid & 63;
    const int j31 = l & 31, h = l >> 5;   // lane index within 32, half-wave
    const int cw = w & 1, iw = w >> 1;    // key-half / d-half, query chunk of 32

    // XCD-aware swizzle: 512 blocks, 64 per XCD -> all 16 blocks of a (b,h) share one L2
    const int bid = ((int)blockIdx.x & 7) * 64 + ((int)blockIdx.x >> 3);
    const int bh = bid >> 4;
    const int m0 = (bid & 15) << 7;       // q-row tile start
    const int bB = bh >> 4;               // batch index (H=16)

    const int* Mg = Mg0 + (size_t)bB * LL;
    float* So = out + SC_OFF + (size_t)bh * LL * LL + (size_t)m0 * LL;
    float* Oo = out + ((size_t)bh * LL + m0) * DD;

    // ---------- prologue: resident Q hi/lo A-fragments ----------
    s16x8 qfh[4], qfl[4];
    if constexpr (BF) {
        const u16* Qh = (const u16*)Qa + ((size_t)bh * LL + m0 + iw * 32 + j31) * DD + h * 8;
        const u16* Ql = (const u16*)Qb + ((size_t)bh * LL + m0 + iw * 32 + j31) * DD + h * 8;
#pragma unroll
        for (int ks = 0; ks < 4; ++ks) {
            qfh[ks] = *(const s16x8*)(Qh + ks * 16);
            qfl[ks] = *(const s16x8*)(Ql + ks * 16);
        }
    } else {
        const float* Qg = (const float*)Qa + ((size_t)bh * LL + m0) * DD;
        const int qi = tid >> 2, qd = (tid & 3) * 16;
        f32x4 qv[4];
        {
            const f32x4* s = (const f32x4*)(Qg + qi * DD + qd);
            qv[0] = s[0]; qv[1] = s[1]; qv[2] = s[2]; qv[3] = s[3];
        }
        u16 qhi[16];
#pragma unroll
        for (int e = 0; e < 16; ++e) qhi[e] = bf16_rne(qv[e >> 2][e & 3]);
        {
            s16x8 a, b;
#pragma unroll
            for (int i = 0; i < 8; ++i) { a[i] = (short)qhi[i]; b[i] = (short)qhi[8 + i]; }
            *(s16x8*)&sm.u.Q[qi][qd] = a;
            *(s16x8*)&sm.u.Q[qi][qd + 8] = b;
        }
        __syncthreads();
#pragma unroll
        for (int ks = 0; ks < 4; ++ks)
            qfh[ks] = *(const s16x8*)&sm.u.Q[iw * 32 + j31][ks * 16 + h * 8];
        __syncthreads();
        {
            s16x8 a, b;
#pragma unroll
            for (int i = 0; i < 8; ++i) {
                a[i] = (short)bf16_rne(qv[i >> 2][i & 3] - bf16f(qhi[i]));
                b[i] = (short)bf16_rne(qv[(8 + i) >> 2][(8 + i) & 3] - bf16f(qhi[8 + i]));
            }
            *(s16x8*)&sm.u.Q[qi][qd] = a;
            *(s16x8*)&sm.u.Q[qi][qd + 8] = b;
        }
        __syncthreads();
#pragma unroll
        for (int ks = 0; ks < 4; ++ks)
            qfl[ks] = *(const s16x8*)&sm.u.Q[iw * 32 + j31][ks * 16 + h * 8];
    }

    f32x16 accO;
#pragma unroll
    for (int e = 0; e < 16; ++e) accO[e] = 0.0f;

    const int kc = tid >> 3, kd = (tid & 7) * 8;     // K staging: row, col base
    const int vc = tid & 63, vd = (tid >> 6) * 8;    // V staging: row, col base
    unsigned char* spw = &sm.u.P[iw][0];
    const int colb = (cw * 32 + j31) * 2;            // P column byte offset for this lane

    for (int t = 0; t < NITER; ++t) {
        const int j0 = t * 64;
        __syncthreads();   // previous iteration done reading Khi/VT/P

        // ---- stage K tile ----
        if constexpr (BF) {
            s16x8 kv = *(const s16x8*)((const u16*)Ka + (size_t)bh * LL * DD + (size_t)(j0 + kc) * DD + kd);
            *(s16x8*)&sm.Khi[kc][kd] = kv;
        } else {
            const f32x4* s = (const f32x4*)((const float*)Ka + (size_t)bh * LL * DD + (size_t)(j0 + kc) * DD + kd);
            f32x4 x = s[0], y = s[1];
            s16x8 kv;
#pragma unroll
            for (int i = 0; i < 4; ++i) { kv[i] = (short)bf16_rne(x[i]); kv[4 + i] = (short)bf16_rne(y[i]); }
            *(s16x8*)&sm.Khi[kc][kd] = kv;
        }
        // ---- stage V^T ----
        if constexpr (BF) {
            s16x8 vv = *(const s16x8*)((const u16*)Va + (size_t)bh * LL * DD + (size_t)(j0 + vc) * DD + vd);
#pragma unroll
            for (int i = 0; i < 8; ++i) sm.VT[vd + i][vc] = (u16)(unsigned short)vv[i];
        } else {
            const f32x4* s = (const f32x4*)((const float*)Va + (size_t)bh * LL * DD + (size_t)(j0 + vc) * DD + vd);
            f32x4 x = s[0], y = s[1];
#pragma unroll
            for (int i = 0; i < 4; ++i) {
                sm.VT[vd + i][vc]     = bf16_rne(x[i]);
                sm.VT[vd + 4 + i][vc] = bf16_rne(y[i]);
            }
        }
        if (tid < 64) sm.bias[tid] = -1.0e9f * (float)Mg[j0 + tid];
        __syncthreads();

        // ---- S = Q * K^T  (A=Q frags, B=K frags -> col=lane=key) ----
        f32x16 accS;
#pragma unroll
        for (int e = 0; e < 16; ++e) accS[e] = 0.0f;
#pragma unroll
        for (int ks = 0; ks < 4; ++ks) {
            s16x8 kf = *(const s16x8*)&sm.Khi[cw * 32 + j31][ks * 16 + h * 8];
            accS = __builtin_amdgcn_mfma_f32_32x32x16_bf16(qfh[ks], kf, accS, 0, 0, 0);
            accS = __builtin_amdgcn_mfma_f32_32x32x16_bf16(qfl[ks], kf, accS, 0, 0, 0);
        }
        // C/D layout: col(key c)=lane&31, row(query i)=(reg&3)+8*(reg>>2)+4*(lane>>5)
        const float bl = sm.bias[cw * 32 + j31];
        float* sp = So + (size_t)(iw * 32 + 4 * h) * LL + j0 + cw * 32 + j31;
#pragma unroll
        for (int g = 0; g < 4; ++g) {
#pragma unroll
            for (int r = 0; r < 4; ++r) {
                float x  = accS[g * 4 + r] * 0.125f + bl;              // qk/8 + mask*(-1e9)
                float tt = __builtin_amdgcn_exp2f(x * 1.44269504f);    // e^x
                float p  = __builtin_amdgcn_logf(1.0f + tt) * 3.38450771757785852e-4f;
                __builtin_nontemporal_store(p, sp + (size_t)(8 * g + r) * LL);  // dense 256B/inst
                const int il = 8 * g + 4 * h + r;                      // local query row
                *(u16*)(spw + ((il * 128 + colb) ^ ((il & 7) << 4))) = bf16_rne(p);
            }
        }
        __syncthreads();   // P from both key-half waves visible

        // ---- OUT^T += V^T * P^T  (wave: d-half cw, i-chunk iw) ----
#pragma unroll
        for (int ks = 0; ks < 4; ++ks) {
            s16x8 va = *(const s16x8*)&sm.VT[cw * 32 + j31][ks * 16 + h * 8];
            s16x8 pb = *(const s16x8*)(spw + ((j31 * 128 + ks * 32 + h * 16) ^ ((j31 & 7) << 4)));
            accO = __builtin_amdgcn_mfma_f32_32x32x16_bf16(va, pb, accO, 0, 0, 0);
        }
    }

    // ---- epilogue: store OUT (lane holds row i = iw*32+j31, 16 d-values) ----
#pragma unroll
    for (int g = 0; g < 4; ++g) {
        f32x4 o;
#pragma unroll
        for (int r = 0; r < 4; ++r) o[r] = accO[g * 4 + r];
        *(f32x4*)(Oo + (size_t)(iw * 32 + j31) * DD + cw * 32 + h * 4 + g * 8) = o;
    }
}

extern "C" void kernel_launch(void* const* d_in, const int* in_sizes, int n_in,
                              void* d_out, int out_size, void* d_ws, size_t ws_size,
                              hipStream_t stream) {
    const float* q    = (const float*)d_in[0];
    const float* k    = (const float*)d_in[1];
    const float* v    = (const float*)d_in[2];
    const int*   mask = (const int*)d_in[5];   // p_q, p_k unused by reference
    float* out = (float*)d_out;

    if (ws_size >= 4ull * TEN * sizeof(u16)) {
        u16* qhi = (u16*)d_ws;
        u16* qlo = qhi + TEN;
        u16* k16 = qlo + TEN;
        u16* v16 = k16 + TEN;
        hipLaunchKernelGGL(psam_prepass, dim3(2048), dim3(256), 0, stream, q, k, v, qhi, qlo, k16, v16);
        hipLaunchKernelGGL((psam_kernel<1>), dim3(512), dim3(512), 0, stream,
                           (const void*)qhi, (const void*)qlo, (const void*)k16, (const void*)v16, mask, out);
    } else {
        hipLaunchKernelGGL((psam_kernel<0>), dim3(512), dim3(512), 0, stream,
                           (const void*)q, (const void*)nullptr, (const void*)k, (const void*)v, mask, out);
    }
}

// Round 4
// 139.334 us; speedup vs baseline: 1.1531x; 1.1531x over previous
//
#include <hip/hip_runtime.h>

typedef float f32x4  __attribute__((ext_vector_type(4)));
typedef float f32x16 __attribute__((ext_vector_type(16)));
typedef short s16x8  __attribute__((ext_vector_type(8)));
typedef unsigned short u16;

#define LL 2048
#define DD 64
#define NITER 32
#define SC_OFF 4194304ull

struct SMem {
    u16 Khi[2][64][72];          // double-buffered key tile, bf16, padded (conflict-free)
    u16 VT [2][64][72];          // double-buffered V^T tile (d rows, c cols)
    union {
        u16 Q[128][72];          // prologue-only staging for Q hi/lo
        unsigned char P[4][4096];// per-iw P tile [i][c] bf16, XOR-swizzled rows
    } u;
};

__device__ __forceinline__ u16 bf16_rne(float x) {
    unsigned u = __builtin_bit_cast(unsigned, x);
    return (u16)((u + 0x7FFFu + ((u >> 16) & 1u)) >> 16);
}
__device__ __forceinline__ float bf16f(u16 h) {
    unsigned u = (unsigned)h << 16;
    return __builtin_bit_cast(float, u);
}

__global__ __launch_bounds__(512, 4)
void psam_kernel(const float* __restrict__ Qg0, const float* __restrict__ Kg0,
                 const float* __restrict__ Vg0, const int* __restrict__ Mg0,
                 float* __restrict__ out)
{
    __shared__ SMem sm;
    const int tid = threadIdx.x;
    const int w = tid >> 6, l = tid & 63;
    const int j31 = l & 31, h = l >> 5;   // lane index within 32, half-wave
    const int cw = w & 1, iw = w >> 1;    // key-half / d-half, query chunk of 32
    const int cwj = cw * 32 + j31;
    const int colb = cwj * 2;

    // XCD-aware swizzle: all 16 blocks of a (b,h) land on one XCD's L2
    const int bid = ((int)blockIdx.x & 7) * 64 + ((int)blockIdx.x >> 3);
    const int bh = bid >> 4;
    const int m0 = (bid & 15) << 7;       // q-row tile start
    const int bB = bh >> 4;               // batch index (H=16)

    const float* Qg = Qg0 + ((size_t)bh * LL + m0) * DD;
    const float* Kg = Kg0 + (size_t)bh * LL * DD;
    const float* Vg = Vg0 + (size_t)bh * LL * DD;
    const int*   Mg = Mg0 + (size_t)bB * LL;
    float* So = out + SC_OFF + (size_t)bh * LL * LL + (size_t)m0 * LL;
    float* Oo = out + ((size_t)bh * LL + m0) * DD;

    // ---------- prologue: stage Q, build resident hi/lo A-fragments ----------
    const int qi = tid >> 2, qd = (tid & 3) * 16;
    f32x4 qv[4];
    {
        const f32x4* s = (const f32x4*)(Qg + qi * DD + qd);
        qv[0] = s[0]; qv[1] = s[1]; qv[2] = s[2]; qv[3] = s[3];
    }
    u16 qhi16[16];
#pragma unroll
    for (int e = 0; e < 16; ++e) qhi16[e] = bf16_rne(qv[e >> 2][e & 3]);
    {
        s16x8 a, b;
#pragma unroll
        for (int i = 0; i < 8; ++i) { a[i] = (short)qhi16[i]; b[i] = (short)qhi16[8 + i]; }
        *(s16x8*)&sm.u.Q[qi][qd] = a;
        *(s16x8*)&sm.u.Q[qi][qd + 8] = b;
    }
    __syncthreads();
    s16x8 qfh[4], qfl[4];
#pragma unroll
    for (int ks = 0; ks < 4; ++ks)
        qfh[ks] = *(const s16x8*)&sm.u.Q[iw * 32 + j31][ks * 16 + h * 8];
    __syncthreads();
    {
        s16x8 a, b;
#pragma unroll
        for (int i = 0; i < 8; ++i) {
            a[i] = (short)bf16_rne(qv[i >> 2][i & 3] - bf16f(qhi16[i]));
            b[i] = (short)bf16_rne(qv[(8 + i) >> 2][(8 + i) & 3] - bf16f(qhi16[8 + i]));
        }
        *(s16x8*)&sm.u.Q[qi][qd] = a;
        *(s16x8*)&sm.u.Q[qi][qd + 8] = b;
    }
    __syncthreads();
#pragma unroll
    for (int ks = 0; ks < 4; ++ks)
        qfl[ks] = *(const s16x8*)&sm.u.Q[iw * 32 + j31][ks * 16 + h * 8];

    // ---------- tile-0 staging + tile-1 register prefetch ----------
    const int kc = tid >> 3, kd = (tid & 7) * 8;     // K staging: row, col base
    const int vc = tid & 63, vd = (tid >> 6) * 8;    // V staging: row, col base
    f32x4 kvx, kvy, vvx, vvy;
    {
        const f32x4* s = (const f32x4*)(Kg + (size_t)kc * DD + kd);
        kvx = s[0]; kvy = s[1];
        const f32x4* s2 = (const f32x4*)(Vg + (size_t)vc * DD + vd);
        vvx = s2[0]; vvy = s2[1];
    }
    {
        s16x8 kv;
#pragma unroll
        for (int i = 0; i < 4; ++i) { kv[i] = (short)bf16_rne(kvx[i]); kv[4 + i] = (short)bf16_rne(kvy[i]); }
        *(s16x8*)&sm.Khi[0][kc][kd] = kv;
#pragma unroll
        for (int i = 0; i < 4; ++i) {
            sm.VT[0][vd + i][vc]     = bf16_rne(vvx[i]);
            sm.VT[0][vd + 4 + i][vc] = bf16_rne(vvy[i]);
        }
    }
    {
        const f32x4* s = (const f32x4*)(Kg + (size_t)(64 + kc) * DD + kd);
        kvx = s[0]; kvy = s[1];
        const f32x4* s2 = (const f32x4*)(Vg + (size_t)(64 + vc) * DD + vd);
        vvx = s2[0]; vvy = s2[1];
    }
    float blc = -1.0e9f * (float)Mg[cwj];
    float bln = -1.0e9f * (float)Mg[64 + cwj];

    f32x16 accO;
#pragma unroll
    for (int e = 0; e < 16; ++e) accO[e] = 0.0f;

    unsigned char* spw = &sm.u.P[iw][0];
    __syncthreads();   // tile-0 staging visible; prologue LDS traffic drained

    int buf = 0;
    for (int t = 0; t < NITER; ++t) {
        const int j0 = t * 64;

        // ---- S = Q * K^T  (A=Q frags, B=K frags -> col=lane=key) ----
        f32x16 accS;
#pragma unroll
        for (int e = 0; e < 16; ++e) accS[e] = 0.0f;
#pragma unroll
        for (int ks = 0; ks < 4; ++ks) {
            s16x8 kf = *(const s16x8*)&sm.Khi[buf][cwj][ks * 16 + h * 8];
            accS = __builtin_amdgcn_mfma_f32_32x32x16_bf16(qfh[ks], kf, accS, 0, 0, 0);
            accS = __builtin_amdgcn_mfma_f32_32x32x16_bf16(qfl[ks], kf, accS, 0, 0, 0);
        }
        // C/D layout: col(key)=lane&31, row(query)=r + 8g + 4h
        const float bl = blc;
        float* sp = So + (size_t)(iw * 32 + 4 * h) * LL + j0 + cwj;
#pragma unroll
        for (int g = 0; g < 4; ++g) {
#pragma unroll
            for (int r = 0; r < 4; ++r) {
                float x  = accS[g * 4 + r] * 0.125f + bl;              // qk/8 + mask*(-1e9)
                float tt = __builtin_amdgcn_exp2f(x * 1.44269504f);    // e^x
                float p  = __builtin_amdgcn_logf(1.0f + tt) * 3.38450771757785852e-4f; // ln(1+e^x)/2048
                __builtin_nontemporal_store(p, sp + (size_t)(8 * g + r) * LL);
                const int il = 8 * g + 4 * h + r;                      // local query row
                *(u16*)(spw + ((il * 128 + colb) ^ ((il & 7) << 4))) = bf16_rne(p);
            }
        }
        asm volatile("s_waitcnt lgkmcnt(0)" ::: "memory");  // P + frag reads drained; NT stores stay in flight
        __builtin_amdgcn_s_barrier();

        // ---- OUT^T += V^T * P^T ----
#pragma unroll
        for (int ks = 0; ks < 4; ++ks) {
            s16x8 va = *(const s16x8*)&sm.VT[buf][cwj][ks * 16 + h * 8];
            s16x8 pb = *(const s16x8*)(spw + ((j31 * 128 + ks * 32 + h * 16) ^ ((j31 & 7) << 4)));
            accO = __builtin_amdgcn_mfma_f32_32x32x16_bf16(va, pb, accO, 0, 0, 0);
        }

        // ---- write tile t+1 staging regs into the other buffer ----
        if (t + 1 < NITER) {
            s16x8 kv;
#pragma unroll
            for (int i = 0; i < 4; ++i) { kv[i] = (short)bf16_rne(kvx[i]); kv[4 + i] = (short)bf16_rne(kvy[i]); }
            *(s16x8*)&sm.Khi[buf ^ 1][kc][kd] = kv;
#pragma unroll
            for (int i = 0; i < 4; ++i) {
                sm.VT[buf ^ 1][vd + i][vc]     = bf16_rne(vvx[i]);
                sm.VT[buf ^ 1][vd + 4 + i][vc] = bf16_rne(vvy[i]);
            }
        }
        // ---- prefetch tile t+2 into registers (full-iteration latency window) ----
        {
            const int tp = (t + 2 < NITER) ? (t + 2) : (NITER - 1);
            const f32x4* s1 = (const f32x4*)(Kg + (size_t)(tp * 64 + kc) * DD + kd);
            kvx = s1[0]; kvy = s1[1];
            const f32x4* s2 = (const f32x4*)(Vg + (size_t)(tp * 64 + vc) * DD + vd);
            vvx = s2[0]; vvy = s2[1];
            blc = bln;
            bln = -1.0e9f * (float)Mg[tp * 64 + cwj];
        }
        asm volatile("s_waitcnt lgkmcnt(0)" ::: "memory");  // staging writes visible; no vmcnt drain
        __builtin_amdgcn_s_barrier();
        buf ^= 1;
    }

    // ---- epilogue: store OUT (lane holds row i = iw*32+j31, 16 d-values) ----
#pragma unroll
    for (int g = 0; g < 4; ++g) {
        f32x4 o;
#pragma unroll
        for (int r = 0; r < 4; ++r) o[r] = accO[g * 4 + r];
        *(f32x4*)(Oo + (size_t)(iw * 32 + j31) * DD + cw * 32 + h * 4 + g * 8) = o;
    }
}

extern "C" void kernel_launch(void* const* d_in, const int* in_sizes, int n_in,
                              void* d_out, int out_size, void* d_ws, size_t ws_size,
                              hipStream_t stream) {
    const float* q    = (const float*)d_in[0];
    const float* k    = (const float*)d_in[1];
    const float* v    = (const float*)d_in[2];
    const int*   mask = (const int*)d_in[5];   // p_q, p_k unused by reference
    float* out = (float*)d_out;
    hipLaunchKernelGGL(psam_kernel, dim3(512), dim3(512), 0, stream, q, k, v, mask, out);
}